// Round 11
// baseline (170.153 us; speedup 1.0000x reference)
//
#include <hip/hip_runtime.h>

#define BB 4
#define QQ 256
#define VV 2048
#define HH 512
#define UU 128

// tanh arg scale folded into projections: C2E = 2*log2(e); exp(x)=exp2(x*LOG2E)
#define C2E   2.8853900817779268f
#define LOG2E 1.4426950408889634f

typedef unsigned short u16;
typedef __attribute__((ext_vector_type(8))) short bf16x8;   // 4 VGPRs = 8 bf16
typedef __attribute__((ext_vector_type(4))) float f32x4;

__device__ __forceinline__ void fma4(float4& a, float s, const float4& w) {
    a.x = fmaf(s, w.x, a.x);
    a.y = fmaf(s, w.y, a.y);
    a.z = fmaf(s, w.z, a.z);
    a.w = fmaf(s, w.w, a.w);
}
__device__ __forceinline__ float2 rcp2(float2 x) {
    return make_float2(__builtin_amdgcn_rcpf(x.x), __builtin_amdgcn_rcpf(x.y));
}
__device__ __forceinline__ float2 mul2(float2 a, float2 b) { return make_float2(a.x*b.x, a.y*b.y); }
__device__ __forceinline__ float2 muls(float2 a, float s)  { return make_float2(a.x*s, a.y*s); }
__device__ __forceinline__ float2 fma2(float2 a, float2 b, float2 c) {
    return make_float2(fmaf(a.x, b.x, c.x), fmaf(a.y, b.y, c.y));
}
__device__ __forceinline__ float2 fmas(float2 a, float s, float2 c) {
    return make_float2(fmaf(a.x, s, c.x), fmaf(a.y, s, c.y));
}
// split x into bf16 hi (truncated) + bf16 lo correction; hi+lo ~= x to ~2^-16
__device__ __forceinline__ void bsplit(float x, u16& h, u16& l) {
    const unsigned bx = __float_as_uint(x);
    h = (u16)(bx >> 16);
    const float lo = x - __uint_as_float(bx & 0xFFFF0000u);
    l = (u16)(__float_as_uint(lo) >> 16);
}

// ---------------------------------------------------------------------------
// Projection GEMM -> EXPONENTIATED, INTERLEAVED transposed output.
// R19: values-blocks ALSO emit valT_hi/lo[b][h][v] (split-bf16 transposed
// values) for the MFMA Phase B. As[kk][r] already holds values[v][h]
// transposed per K-tile, so the store is a cheap per-element split.
// ---------------------------------------------------------------------------
__global__ __launch_bounds__(256) void proj_kernel(const float* __restrict__ queries,
                                                   const float* __restrict__ values,
                                                   const float* __restrict__ w1,
                                                   const float* __restrict__ w2,
                                                   float* __restrict__ pqI,
                                                   float* __restrict__ pvI,
                                                   float* __restrict__ denom,
                                                   u16* __restrict__ vTh,
                                                   u16* __restrict__ vTl) {
    __shared__ float smem[32 * 36 + 32 * 128];   // As[32][36] | Ws[32*128]; Ls aliases
    float (*As)[36] = (float(*)[36])smem;        // [k][row], stride 36 (16B-aligned rows)
    float* Ws = smem + 32 * 36;                  // [k][u]
    float (*Ls)[36] = (float(*)[36])smem;        // [u][row], epilogue (after barrier)

    const int bid = blockIdx.x;
    const int tid = threadIdx.x;
    if (bid == 0) *(float4*)&denom[tid * 4] = make_float4(0.f, 0.f, 0.f, 0.f);

    const bool isv = (bid < 256);
    const float* A; const float* W; int b, r0, ROWS; float* Ob;
    if (isv) {                             // values: 8192 rows, 64 blocks/batch
        b = bid >> 6; r0 = (bid & 63) * 32;
        A = values + ((size_t)(b * VV + r0)) * HH;  W = w2;
        Ob = pvI + (size_t)b * UU * VV;  ROWS = VV;
    } else {                               // queries: 1024 rows, 8 blocks/batch
        const int q = bid - 256;
        b = q >> 3; r0 = (q & 7) * 32;
        A = queries + ((size_t)(b * QQ + r0)) * HH; W = w1;
        Ob = pqI + (size_t)b * UU * QQ;  ROWS = QQ;
    }

    const int tx = tid & 31;         // u-group: u = tx*4 .. tx*4+3
    const int ty = tid >> 5;         // row-quad: rows 4ty .. 4ty+3
    float4 acc[4];
#pragma unroll
    for (int j = 0; j < 4; j++) acc[j] = make_float4(0.f, 0.f, 0.f, 0.f);

    for (int k0 = 0; k0 < HH; k0 += 32) {
        {   // A tile: 32 rows x 32 k, transposed store; one float4 per thread
            const int r = tid >> 3, kk4 = (tid & 7) * 4;
            const float4 a = *(const float4*)&A[(size_t)r * HH + k0 + kk4];
            As[kk4 + 0][r] = a.x; As[kk4 + 1][r] = a.y;
            As[kk4 + 2][r] = a.z; As[kk4 + 3][r] = a.w;
        }
#pragma unroll
        for (int t = 0; t < 4; t++) {  // W tile: 32 k x 128 u
            const int f = tid + t * 256;
            const int kk = f >> 5, u4 = (f & 31) * 4;
            *(float4*)&Ws[kk * 128 + u4] = *(const float4*)&W[(size_t)(k0 + kk) * UU + u4];
        }
        __syncthreads();
#pragma unroll
        for (int kk = 0; kk < 32; kk++) {
            const float4 a = *(const float4*)&As[kk][ty * 4];       // 4 rows
            const float4 w = *(const float4*)&Ws[kk * 128 + tx * 4];
            fma4(acc[0], a.x, w);
            fma4(acc[1], a.y, w);
            fma4(acc[2], a.z, w);
            fma4(acc[3], a.w, w);
        }
        if (isv) {   // emit split-bf16 transposed values: valT[b][h=k0+kk][v=r0+r]
#pragma unroll
            for (int t = 0; t < 4; t++) {
                const int kk = (tid >> 5) + 8 * t;
                const int r  = tid & 31;
                u16 h16, l16;
                bsplit(As[kk][r], h16, l16);
                const size_t o = ((size_t)b * HH + k0 + kk) * VV + r0 + r;
                vTh[o] = h16; vTl[o] = l16;
            }
        }
        __syncthreads();
    }
    // epilogue: exp2 + transpose via Ls (aliases As/Ws — barrier passed above)
#pragma unroll
    for (int j = 0; j < 4; j++) {
        const float aa[4] = {acc[j].x, acc[j].y, acc[j].z, acc[j].w};
#pragma unroll
        for (int i = 0; i < 4; i++)
            Ls[tx * 4 + i][ty * 4 + j] = __builtin_amdgcn_exp2f(aa[i] * C2E);
    }
    __syncthreads();
#pragma unroll
    for (int t = 0; t < 4; t++) {    // 1024 float4 chunks: (g = idx>>5, r = idx&31)
        const int idx = tid + t * 256;
        const int g = idx >> 5, r = idx & 31;
        float4 o;
        o.x = Ls[4 * g + 0][r]; o.y = Ls[4 * g + 1][r];
        o.z = Ls[4 * g + 2][r]; o.w = Ls[4 * g + 3][r];
        *(float4*)&Ob[((size_t)g * ROWS + r0 + r) * 4] = o;
    }
}

// ---------------------------------------------------------------------------
// R19 fused: Phase A = R18 (72us measured, Eq via LDS). Phase B REWRITTEN as
// split-bf16 MFMA GEMM: out16q x 512h += att[512v][16q] * val[512v][512h].
// att -> LDS transposed bf16 hi/lo (attH/attL[16][520], ds_read_b128 frags);
// values -> global valT_hi/lo[b][h][v] (16B loads). 3 MFMAs per (K-step,
// n-tile): aH*bH + aL*bH + aH*bL (error ~2^-15; denominator stays fp32).
// Each wave owns 32 h for ALL 16 q -> no cross-wave reduce, B-scratch and
// its 4 barriers deleted. LDS 74.8KB.
// Phase B VALU work (4096 scalar FMAs/thread = ~14us chip floor) moves to
// matrix pipe (~1us) + L2 streaming (~7us/CU).
// ---------------------------------------------------------------------------
__global__ __launch_bounds__(1024, 8) void fused_kernel(const float* __restrict__ pqI,
                                                        const float* __restrict__ pvI,
                                                        const float* __restrict__ vvec,
                                                        const u16* __restrict__ vTh,
                                                        const u16* __restrict__ vTl,
                                                        float* __restrict__ slab,
                                                        float* __restrict__ denom) {
    __shared__ __attribute__((aligned(16))) u16 attH[16 * 520];  // [q][v] bf16-hi, pad 8
    __shared__ __attribute__((aligned(16))) u16 attL[16 * 520];  // [q][v] bf16-lo
    __shared__ float scratch[16 * 512];   // 32KB: A-combine cbuf only
    __shared__ float wred[8][16];
    __shared__ float eqs[32 * 64];        // 8KB: Eq tile [G][16q x 4u]
    const int tid = threadIdx.x;
    const int bid = blockIdx.x;
    const int vs = bid & 3, qb = (bid >> 2) & 15, b = bid >> 6;
    const int qbase = qb * 16, vbase = vs * 512;

    // ---- Phase A ----
    const int vloc = tid & 511;
    const int uh = tid >> 9;          // wave-uniform u-half
    const int v = vbase + vloc;

    const float* pv4 = pvI + (size_t)b * UU * VV + (size_t)v * 4;      // Ev
    const float* pq4 = pqI + (size_t)b * UU * QQ + (size_t)qbase * 4;  // Eq block (16q x 4u per G)

    // stage Eq tile: 512 float4 (64B per G, contiguous), coalesced
    if (tid < 512) {
        const int G = tid >> 4, f4 = tid & 15;
        *(float4*)&eqs[G * 64 + f4 * 4] = *(const float4*)&pq4[(size_t)G * QQ * 4 + f4 * 4];
    }

    float vsum = 0.0f;
#pragma unroll
    for (int u4 = 0; u4 < UU; u4 += 4) {
        const float4 t = *(const float4*)&vvec[u4];
        vsum += t.x + t.y + t.z + t.w;
    }

    float2 acc[8];
#pragma unroll
    for (int p = 0; p < 8; p++) acc[p] = make_float2(0.f, 0.f);

    const int G0 = uh * 16;
    float4 ev = *(const float4*)&pv4[(size_t)G0 * VV * 4];   // prefetch g=0
    __syncthreads();   // Eq staged

    for (int g = 0; g < 16; g++) {
        const int G = G0 + g;
        const float* eqp = &eqs[G * 64];              // LDS, uniform -> broadcast
        float4 evn;
        if (g < 15) evn = *(const float4*)&pv4[(size_t)(G + 1) * VV * 4];
        const float4 wq = *(const float4*)&vvec[G * 4];
        const float w0 = 2.f * wq.x, w1 = 2.f * wq.y;
        const float w2 = 2.f * wq.z, w3 = 2.f * wq.w;
#pragma unroll
        for (int p = 0; p < 8; p++) {
            const float4 e0 = *(const float4*)&eqp[(2 * p) * 4];      // q=2p (ds_read_b128)
            const float4 e1 = *(const float4*)&eqp[(2 * p + 1) * 4];  // q=2p+1
            const float2 a1 = make_float2(fmaf(e0.x, ev.x, 1.f), fmaf(e1.x, ev.x, 1.f));
            const float2 b1 = make_float2(fmaf(e0.y, ev.y, 1.f), fmaf(e1.y, ev.y, 1.f));
            const float2 c1 = make_float2(fmaf(e0.z, ev.z, 1.f), fmaf(e1.z, ev.z, 1.f));
            const float2 d1 = make_float2(fmaf(e0.w, ev.w, 1.f), fmaf(e1.w, ev.w, 1.f));
            const float2 pab = mul2(a1, b1), pcd = mul2(c1, d1);
            const float2 nab = fmas(a1, w1, muls(b1, w0));   // w0*b1 + w1*a1
            const float2 ncd = fmas(c1, w3, muls(d1, w2));
            const float2 num = fma2(nab, pcd, mul2(ncd, pab));
            const float2 den = mul2(pab, pcd);
            acc[p] = fma2(num, rcp2(den), acc[p]);
        }
        ev = evn;
    }

    // combine u-halves: uh=1 -> cbuf (q-major, lane-consecutive b32), uh=0 finishes
    float* cb = scratch;   // [q][vloc], 16*512 floats
    if (uh == 1) {
#pragma unroll
        for (int p = 0; p < 8; p++) {
            cb[(2 * p + 0) * 512 + vloc] = acc[p].x;
            cb[(2 * p + 1) * 512 + vloc] = acc[p].y;
        }
    }
    __syncthreads();
    if (uh == 0) {
#pragma unroll
        for (int p = 0; p < 8; p++) {
            const float hx = cb[(2 * p + 0) * 512 + vloc];
            const float hy = cb[(2 * p + 1) * 512 + vloc];
            float2 e;
            e.x = __builtin_amdgcn_exp2f((vsum - (acc[p].x + hx)) * LOG2E);
            e.y = __builtin_amdgcn_exp2f((vsum - (acc[p].y + hy)) * LOG2E);
            // split-bf16 transposed att for MFMA A-frags
            u16 hh, ll;
            bsplit(e.x, hh, ll);
            attH[(2 * p + 0) * 520 + vloc] = hh; attL[(2 * p + 0) * 520 + vloc] = ll;
            bsplit(e.y, hh, ll);
            attH[(2 * p + 1) * 520 + vloc] = hh; attL[(2 * p + 1) * 520 + vloc] = ll;
            acc[p] = e;
        }
#pragma unroll
        for (int off = 1; off < 64; off <<= 1) {
#pragma unroll
            for (int p = 0; p < 8; p++) {
                acc[p].x += __shfl_xor(acc[p].x, off, 64);
                acc[p].y += __shfl_xor(acc[p].y, off, 64);
            }
        }
        if ((tid & 63) == 0) {
            const int w = tid >> 6;   // 0..7 (uh=0 waves)
#pragma unroll
            for (int p = 0; p < 8; p++) {
                wred[w][2 * p + 0] = acc[p].x;
                wred[w][2 * p + 1] = acc[p].y;
            }
        }
    }
    __syncthreads();
    if (tid < 16) {
        float s = 0.f;
#pragma unroll
        for (int w = 0; w < 8; w++) s += wred[w][tid];
        atomicAdd(&denom[b * QQ + qbase + tid], s);
    }

    // ---- Phase B: MFMA. wave w -> h0 = 32w (2 n-tiles of 16), all 16 q ----
    const int ln = tid & 63, wv = tid >> 6;
    const int m = ln & 15, g4 = ln >> 4;
    const int h0 = wv * 32;
    const u16* vtH0 = vTh + ((size_t)(b * HH + h0 + m)) * VV + vbase;
    const u16* vtL0 = vTl + ((size_t)(b * HH + h0 + m)) * VV + vbase;
    const u16* vtH1 = vtH0 + (size_t)16 * VV;
    const u16* vtL1 = vtL0 + (size_t)16 * VV;

    f32x4 acc0 = {0.f, 0.f, 0.f, 0.f}, acc1 = {0.f, 0.f, 0.f, 0.f};
#pragma unroll 4
    for (int kk = 0; kk < 16; kk++) {
        const int vk = kk * 32 + g4 * 8;
        const bf16x8 aH = *(const bf16x8*)&attH[m * 520 + vk];   // ds_read_b128
        const bf16x8 aL = *(const bf16x8*)&attL[m * 520 + vk];
        const bf16x8 bH0 = *(const bf16x8*)&vtH0[vk];            // global dwordx4
        const bf16x8 bL0 = *(const bf16x8*)&vtL0[vk];
        const bf16x8 bH1 = *(const bf16x8*)&vtH1[vk];
        const bf16x8 bL1 = *(const bf16x8*)&vtL1[vk];
        acc0 = __builtin_amdgcn_mfma_f32_16x16x32_bf16(aH, bH0, acc0, 0, 0, 0);
        acc1 = __builtin_amdgcn_mfma_f32_16x16x32_bf16(aH, bH1, acc1, 0, 0, 0);
        acc0 = __builtin_amdgcn_mfma_f32_16x16x32_bf16(aL, bH0, acc0, 0, 0, 0);
        acc1 = __builtin_amdgcn_mfma_f32_16x16x32_bf16(aL, bH1, acc1, 0, 0, 0);
        acc0 = __builtin_amdgcn_mfma_f32_16x16x32_bf16(aH, bL0, acc0, 0, 0, 0);
        acc1 = __builtin_amdgcn_mfma_f32_16x16x32_bf16(aH, bL1, acc1, 0, 0, 0);
    }
    // D layout (m89): col = lane&15 (h), row = (lane>>4)*4 + reg (q)
    float* sp = slab + (size_t)vs * (BB * QQ * HH) + ((size_t)(b * QQ + qbase)) * HH;
#pragma unroll
    for (int i = 0; i < 4; i++) {
        sp[(size_t)(g4 * 4 + i) * HH + h0 + m]      = acc0[i];
        sp[(size_t)(g4 * 4 + i) * HH + h0 + 16 + m] = acc1[i];
    }
}

// ---------------------------------------------------------------------------
// out = (sum of 4 slabs) * rcp(denom[row]). 131072 float4s, grid 512.
// ---------------------------------------------------------------------------
__global__ __launch_bounds__(256) void reduce_kernel(const float* __restrict__ slab,
                                                     const float* __restrict__ denom,
                                                     float* __restrict__ out) {
    const int i = blockIdx.x * 256 + threadIdx.x;    // float4 index
    const float r = __builtin_amdgcn_rcpf(denom[i >> 7]);
    const float4* s4 = (const float4*)slab;
    float4 s = s4[i];
#pragma unroll
    for (int k = 1; k < 4; k++) {
        const float4 p = s4[(size_t)k * (BB * QQ * HH / 4) + i];
        s.x += p.x; s.y += p.y; s.z += p.z; s.w += p.w;
    }
    s.x *= r; s.y *= r; s.z *= r; s.w *= r;
    ((float4*)out)[i] = s;
}

// ---------------------------------------------------------------------------
extern "C" void kernel_launch(void* const* d_in, const int* in_sizes, int n_in,
                              void* d_out, int out_size, void* d_ws, size_t ws_size,
                              hipStream_t stream) {
    const float* queries = (const float*)d_in[0];  // [B,Q,H]
    const float* values  = (const float*)d_in[1];  // [B,V,H]
    const float* w1      = (const float*)d_in[2];  // [H,U]
    const float* w2      = (const float*)d_in[3];  // [H,U]
    const float* vvec    = (const float*)d_in[4];  // [U]
    float* out = (float*)d_out;

    // ws (floats): pqI[131072] | pvI[1048576] | denom[1024] | slab[4*524288]
    //            | valT_hi[8MB as u16] | valT_lo[8MB as u16]   (~30MB total)
    float* ws    = (float*)d_ws;
    float* pqI   = ws;
    float* pvI   = pqI + BB * UU * QQ;
    float* denom = pvI + (size_t)BB * UU * VV;
    float* slab  = denom + BB * QQ;
    u16*   vTh   = (u16*)(slab + (size_t)4 * BB * QQ * HH);
    u16*   vTl   = vTh + (size_t)BB * HH * VV;

    proj_kernel<<<256 + 32, 256, 0, stream>>>(queries, values, w1, w2, pqI, pvI, denom, vTh, vTl);
    fused_kernel<<<BB * (QQ / 16) * (VV / 512), 1024, 0, stream>>>(pqI, pvI, vvec, vTh, vTl, slab, denom);
    reduce_kernel<<<(BB * QQ * HH) / 4 / 256, 256, 0, stream>>>(slab, denom, out);
}

// Round 14
// 167.959 us; speedup vs baseline: 1.0131x; 1.0131x over previous
//
#include <hip/hip_runtime.h>

#define BB 4
#define QQ 256
#define VV 2048
#define HH 512
#define UU 128

// tanh arg scale folded into projections: C2E = 2*log2(e); exp(x)=exp2(x*LOG2E)
#define C2E   2.8853900817779268f
#define LOG2E 1.4426950408889634f

__device__ __forceinline__ void fma4(float4& a, float s, const float4& w) {
    a.x = fmaf(s, w.x, a.x);
    a.y = fmaf(s, w.y, a.y);
    a.z = fmaf(s, w.z, a.z);
    a.w = fmaf(s, w.w, a.w);
}
__device__ __forceinline__ float2 rcp2(float2 x) {
    return make_float2(__builtin_amdgcn_rcpf(x.x), __builtin_amdgcn_rcpf(x.y));
}
__device__ __forceinline__ float2 mul2(float2 a, float2 b) { return make_float2(a.x*b.x, a.y*b.y); }
__device__ __forceinline__ float2 muls(float2 a, float s)  { return make_float2(a.x*s, a.y*s); }
__device__ __forceinline__ float2 fma2(float2 a, float2 b, float2 c) {
    return make_float2(fmaf(a.x, b.x, c.x), fmaf(a.y, b.y, c.y));
}
__device__ __forceinline__ float2 fmas(float2 a, float s, float2 c) {
    return make_float2(fmaf(a.x, s, c.x), fmaf(a.y, s, c.y));
}

// ---------------------------------------------------------------------------
// Projection GEMM -> EXPONENTIATED, INTERLEAVED transposed output.
// (R12 version, known-good, ~13us by R17 budget calibration.)
// ---------------------------------------------------------------------------
__global__ __launch_bounds__(256) void proj_kernel(const float* __restrict__ queries,
                                                   const float* __restrict__ values,
                                                   const float* __restrict__ w1,
                                                   const float* __restrict__ w2,
                                                   float* __restrict__ pqI,
                                                   float* __restrict__ pvI,
                                                   float* __restrict__ denom) {
    __shared__ float smem[32 * 36 + 32 * 128];   // As[32][36] | Ws[32*128]; Ls aliases
    float (*As)[36] = (float(*)[36])smem;        // [k][row], stride 36 (16B-aligned rows)
    float* Ws = smem + 32 * 36;                  // [k][u]
    float (*Ls)[36] = (float(*)[36])smem;        // [u][row], epilogue (after barrier)

    const int bid = blockIdx.x;
    const int tid = threadIdx.x;
    if (bid == 0) *(float4*)&denom[tid * 4] = make_float4(0.f, 0.f, 0.f, 0.f);

    const bool isv = (bid < 256);
    const float* A; const float* W; int b, r0, ROWS; float* Ob;
    if (isv) {                             // values: 8192 rows, 64 blocks/batch
        b = bid >> 6; r0 = (bid & 63) * 32;
        A = values + ((size_t)(b * VV + r0)) * HH;  W = w2;
        Ob = pvI + (size_t)b * UU * VV;  ROWS = VV;
    } else {                               // queries: 1024 rows, 8 blocks/batch
        const int q = bid - 256;
        b = q >> 3; r0 = (q & 7) * 32;
        A = queries + ((size_t)(b * QQ + r0)) * HH; W = w1;
        Ob = pqI + (size_t)b * UU * QQ;  ROWS = QQ;
    }

    const int tx = tid & 31;         // u-group: u = tx*4 .. tx*4+3
    const int ty = tid >> 5;         // row-quad: rows 4ty .. 4ty+3
    float4 acc[4];
#pragma unroll
    for (int j = 0; j < 4; j++) acc[j] = make_float4(0.f, 0.f, 0.f, 0.f);

    for (int k0 = 0; k0 < HH; k0 += 32) {
        {   // A tile: 32 rows x 32 k, transposed store; one float4 per thread
            const int r = tid >> 3, kk4 = (tid & 7) * 4;
            const float4 a = *(const float4*)&A[(size_t)r * HH + k0 + kk4];
            As[kk4 + 0][r] = a.x; As[kk4 + 1][r] = a.y;
            As[kk4 + 2][r] = a.z; As[kk4 + 3][r] = a.w;
        }
#pragma unroll
        for (int t = 0; t < 4; t++) {  // W tile: 32 k x 128 u
            const int f = tid + t * 256;
            const int kk = f >> 5, u4 = (f & 31) * 4;
            *(float4*)&Ws[kk * 128 + u4] = *(const float4*)&W[(size_t)(k0 + kk) * UU + u4];
        }
        __syncthreads();
#pragma unroll
        for (int kk = 0; kk < 32; kk++) {
            const float4 a = *(const float4*)&As[kk][ty * 4];       // 4 rows
            const float4 w = *(const float4*)&Ws[kk * 128 + tx * 4];
            fma4(acc[0], a.x, w);
            fma4(acc[1], a.y, w);
            fma4(acc[2], a.z, w);
            fma4(acc[3], a.w, w);
        }
        __syncthreads();
    }
    // epilogue: exp2 + transpose via Ls (aliases As/Ws — barrier passed above)
#pragma unroll
    for (int j = 0; j < 4; j++) {
        const float aa[4] = {acc[j].x, acc[j].y, acc[j].z, acc[j].w};
#pragma unroll
        for (int i = 0; i < 4; i++)
            Ls[tx * 4 + i][ty * 4 + j] = __builtin_amdgcn_exp2f(aa[i] * C2E);
    }
    __syncthreads();
#pragma unroll
    for (int t = 0; t < 4; t++) {    // 1024 float4 chunks: (g = idx>>5, r = idx&31)
        const int idx = tid + t * 256;
        const int g = idx >> 5, r = idx & 31;
        float4 o;
        o.x = Ls[4 * g + 0][r]; o.y = Ls[4 * g + 1][r];
        o.z = Ls[4 * g + 2][r]; o.w = Ls[4 * g + 3][r];
        *(float4*)&Ob[((size_t)g * ROWS + r0 + r) * 4] = o;
    }
}

// ---------------------------------------------------------------------------
// R18 fused (CHAMPION, 72.0us measured): R12 structure with the Eq tile
// (8KB per block: 32G x 16q x 4u) staged into LDS once; Phase A reads e0/e1
// via uniform ds_read_b128 broadcasts instead of s_load_dwordx4 (the scalar
// cache wall was worth -5.2us). vs=4, grid 256 = 1 block/CU, 16 waves.
// Evidence ledger on the remaining ~30us stall: occupancy 2x-8x (null),
// bank conflicts (0), prefetch pinning (hurts), VGPR relax (no-op), MFMA
// Phase B (-17us VALU, 0us duration), fission (+60), coop fusion (+100).
// No pipe counter >60%. Local optimum under available evidence.
// ---------------------------------------------------------------------------
__global__ __launch_bounds__(1024, 8) void fused_kernel(const float* __restrict__ pqI,
                                                        const float* __restrict__ pvI,
                                                        const float* __restrict__ vvec,
                                                        const float* __restrict__ values,
                                                        float* __restrict__ slab,
                                                        float* __restrict__ denom) {
    __shared__ float att[512][20];        // [v][q] padded; persists A->B
    __shared__ float scratch[24 * 512];   // 48KB: A-combine cbuf [16][512] / B-scratch [24][512]
    __shared__ float wred[8][16];
    __shared__ float eqs[32 * 64];        // 8KB: Eq tile [G][16q x 4u]
    const int tid = threadIdx.x;
    const int bid = blockIdx.x;
    const int vs = bid & 3, qb = (bid >> 2) & 15, b = bid >> 6;
    const int qbase = qb * 16, vbase = vs * 512;

    // ---- Phase A ----
    const int vloc = tid & 511;
    const int uh = tid >> 9;          // wave-uniform u-half
    const int v = vbase + vloc;

    const float* pv4 = pvI + (size_t)b * UU * VV + (size_t)v * 4;      // Ev
    const float* pq4 = pqI + (size_t)b * UU * QQ + (size_t)qbase * 4;  // Eq block (16q x 4u per G)

    // stage Eq tile: 512 float4 (64B per G, contiguous), coalesced
    if (tid < 512) {
        const int G = tid >> 4, f4 = tid & 15;
        *(float4*)&eqs[G * 64 + f4 * 4] = *(const float4*)&pq4[(size_t)G * QQ * 4 + f4 * 4];
    }

    float vsum = 0.0f;
#pragma unroll
    for (int u4 = 0; u4 < UU; u4 += 4) {
        const float4 t = *(const float4*)&vvec[u4];
        vsum += t.x + t.y + t.z + t.w;
    }

    float2 acc[8];
#pragma unroll
    for (int p = 0; p < 8; p++) acc[p] = make_float2(0.f, 0.f);

    const int G0 = uh * 16;
    float4 ev = *(const float4*)&pv4[(size_t)G0 * VV * 4];   // prefetch g=0
    __syncthreads();   // Eq staged

    for (int g = 0; g < 16; g++) {
        const int G = G0 + g;
        const float* eqp = &eqs[G * 64];              // LDS, uniform -> broadcast
        float4 evn;
        if (g < 15) evn = *(const float4*)&pv4[(size_t)(G + 1) * VV * 4];
        const float4 wq = *(const float4*)&vvec[G * 4];
        const float w0 = 2.f * wq.x, w1 = 2.f * wq.y;
        const float w2 = 2.f * wq.z, w3 = 2.f * wq.w;
#pragma unroll
        for (int p = 0; p < 8; p++) {
            const float4 e0 = *(const float4*)&eqp[(2 * p) * 4];      // q=2p (ds_read_b128)
            const float4 e1 = *(const float4*)&eqp[(2 * p + 1) * 4];  // q=2p+1
            const float2 a1 = make_float2(fmaf(e0.x, ev.x, 1.f), fmaf(e1.x, ev.x, 1.f));
            const float2 b1 = make_float2(fmaf(e0.y, ev.y, 1.f), fmaf(e1.y, ev.y, 1.f));
            const float2 c1 = make_float2(fmaf(e0.z, ev.z, 1.f), fmaf(e1.z, ev.z, 1.f));
            const float2 d1 = make_float2(fmaf(e0.w, ev.w, 1.f), fmaf(e1.w, ev.w, 1.f));
            const float2 pab = mul2(a1, b1), pcd = mul2(c1, d1);
            const float2 nab = fmas(a1, w1, muls(b1, w0));   // w0*b1 + w1*a1
            const float2 ncd = fmas(c1, w3, muls(d1, w2));
            const float2 num = fma2(nab, pcd, mul2(ncd, pab));
            const float2 den = mul2(pab, pcd);
            acc[p] = fma2(num, rcp2(den), acc[p]);
        }
        ev = evn;
    }

    // combine u-halves: uh=1 -> cbuf (q-major, lane-consecutive b32), uh=0 finishes
    float* cb = scratch;   // [q][vloc], 16*512 floats
    if (uh == 1) {
#pragma unroll
        for (int p = 0; p < 8; p++) {
            cb[(2 * p + 0) * 512 + vloc] = acc[p].x;
            cb[(2 * p + 1) * 512 + vloc] = acc[p].y;
        }
    }
    __syncthreads();
    if (uh == 0) {
#pragma unroll
        for (int p = 0; p < 8; p++) {
            const float hx = cb[(2 * p + 0) * 512 + vloc];
            const float hy = cb[(2 * p + 1) * 512 + vloc];
            float2 e;
            e.x = __builtin_amdgcn_exp2f((vsum - (acc[p].x + hx)) * LOG2E);
            e.y = __builtin_amdgcn_exp2f((vsum - (acc[p].y + hy)) * LOG2E);
            *(float2*)&att[vloc][2 * p] = e;
            acc[p] = e;
        }
#pragma unroll
        for (int off = 1; off < 64; off <<= 1) {
#pragma unroll
            for (int p = 0; p < 8; p++) {
                acc[p].x += __shfl_xor(acc[p].x, off, 64);
                acc[p].y += __shfl_xor(acc[p].y, off, 64);
            }
        }
        if ((tid & 63) == 0) {
            const int w = tid >> 6;   // 0..7 (uh=0 waves)
#pragma unroll
            for (int p = 0; p < 8; p++) {
                wred[w][2 * p + 0] = acc[p].x;
                wred[w][2 * p + 1] = acc[p].y;
            }
        }
    }
    __syncthreads();
    if (tid < 16) {
        float s = 0.f;
#pragma unroll
        for (int w = 0; w < 8; w++) s += wred[w][tid];
        atomicAdd(&denom[b * QQ + qbase + tid], s);
    }

    // ---- Phase B: (qh: 8 q, vh: 4 v-quarters of 128) across 8 half-waves ----
    const int hg = tid & 127, sel = tid >> 7;       // sel wave-uniform
    const int qh = sel & 1, vh = sel >> 1;          // vh 0..3
    const int h0 = hg * 4;
    const float* vp = values + ((size_t)(b * VV + vbase + vh * 128)) * HH + h0;

    float4 oacc[8];
#pragma unroll
    for (int j = 0; j < 8; j++) oacc[j] = make_float4(0.f, 0.f, 0.f, 0.f);

#pragma unroll 2
    for (int vv = 0; vv < 128; vv++) {
        const float4 w = *(const float4*)&vp[(size_t)vv * HH];
        const float4 a0 = *(const float4*)&att[vh * 128 + vv][qh * 8 + 0];  // broadcast
        const float4 a1 = *(const float4*)&att[vh * 128 + vv][qh * 8 + 4];
        fma4(oacc[0], a0.x, w); fma4(oacc[1], a0.y, w);
        fma4(oacc[2], a0.z, w); fma4(oacc[3], a0.w, w);
        fma4(oacc[4], a1.x, w); fma4(oacc[5], a1.y, w);
        fma4(oacc[6], a1.z, w); fma4(oacc[7], a1.w, w);
    }

    // epilogue: 2 rounds over qh; vh 1..3 stage to 3 LDS buffers, vh 0 sums+stores
    float (*scr)[512] = (float(*)[512])scratch;   // 24 rows x 512
    for (int rr = 0; rr < 2; rr++) {
        __syncthreads();
        if (qh == rr && vh > 0) {
#pragma unroll
            for (int j = 0; j < 8; j++)
                *(float4*)&scr[(vh - 1) * 8 + j][h0] = oacc[j];
        }
        __syncthreads();
        if (qh == rr && vh == 0) {
            float* sp = slab + (size_t)vs * (BB * QQ * HH);
#pragma unroll
            for (int j = 0; j < 8; j++) {
                const float4 p0 = *(const float4*)&scr[0 * 8 + j][h0];
                const float4 p1 = *(const float4*)&scr[1 * 8 + j][h0];
                const float4 p2 = *(const float4*)&scr[2 * 8 + j][h0];
                float4 o;
                o.x = oacc[j].x + p0.x + p1.x + p2.x;
                o.y = oacc[j].y + p0.y + p1.y + p2.y;
                o.z = oacc[j].z + p0.z + p1.z + p2.z;
                o.w = oacc[j].w + p0.w + p1.w + p2.w;
                *(float4*)&sp[((size_t)(b * QQ + qbase + rr * 8 + j)) * HH + h0] = o;
            }
        }
    }
}

// ---------------------------------------------------------------------------
// out = (sum of 4 slabs) * rcp(denom[row]). 131072 float4s, grid 512.
// ---------------------------------------------------------------------------
__global__ __launch_bounds__(256) void reduce_kernel(const float* __restrict__ slab,
                                                     const float* __restrict__ denom,
                                                     float* __restrict__ out) {
    const int i = blockIdx.x * 256 + threadIdx.x;    // float4 index
    const float r = __builtin_amdgcn_rcpf(denom[i >> 7]);
    const float4* s4 = (const float4*)slab;
    float4 s = s4[i];
#pragma unroll
    for (int k = 1; k < 4; k++) {
        const float4 p = s4[(size_t)k * (BB * QQ * HH / 4) + i];
        s.x += p.x; s.y += p.y; s.z += p.z; s.w += p.w;
    }
    s.x *= r; s.y *= r; s.z *= r; s.w *= r;
    ((float4*)out)[i] = s;
}

// ---------------------------------------------------------------------------
extern "C" void kernel_launch(void* const* d_in, const int* in_sizes, int n_in,
                              void* d_out, int out_size, void* d_ws, size_t ws_size,
                              hipStream_t stream) {
    const float* queries = (const float*)d_in[0];  // [B,Q,H]
    const float* values  = (const float*)d_in[1];  // [B,V,H]
    const float* w1      = (const float*)d_in[2];  // [H,U]
    const float* w2      = (const float*)d_in[3];  // [H,U]
    const float* vvec    = (const float*)d_in[4];  // [U]
    float* out = (float*)d_out;

    // ws (floats): pqI[131072] | pvI[1048576] | denom[1024] | slab[4*524288]
    float* ws    = (float*)d_ws;
    float* pqI   = ws;
    float* pvI   = pqI + BB * UU * QQ;
    float* denom = pvI + (size_t)BB * UU * VV;
    float* slab  = denom + BB * QQ;

    proj_kernel<<<256 + 32, 256, 0, stream>>>(queries, values, w1, w2, pqI, pvI, denom);
    fused_kernel<<<BB * (QQ / 16) * (VV / 512), 1024, 0, stream>>>(pqI, pvI, vvec, values, slab, denom);
    reduce_kernel<<<(BB * QQ * HH) / 4 / 256, 256, 0, stream>>>(slab, denom, out);
}

// Round 15
// 167.597 us; speedup vs baseline: 1.0153x; 1.0022x over previous
//
#include <hip/hip_runtime.h>

#define BB 4
#define QQ 256
#define VV 2048
#define HH 512
#define UU 128

// tanh arg scale folded into projections: C2E = 2*log2(e); exp(x)=exp2(x*LOG2E)
#define C2E   2.8853900817779268f
#define LOG2E 1.4426950408889634f

__device__ __forceinline__ void fma4(float4& a, float s, const float4& w) {
    a.x = fmaf(s, w.x, a.x);
    a.y = fmaf(s, w.y, a.y);
    a.z = fmaf(s, w.z, a.z);
    a.w = fmaf(s, w.w, a.w);
}
__device__ __forceinline__ float2 rcp2(float2 x) {
    return make_float2(__builtin_amdgcn_rcpf(x.x), __builtin_amdgcn_rcpf(x.y));
}
__device__ __forceinline__ float2 mul2(float2 a, float2 b) { return make_float2(a.x*b.x, a.y*b.y); }
__device__ __forceinline__ float2 muls(float2 a, float s)  { return make_float2(a.x*s, a.y*s); }
__device__ __forceinline__ float2 fma2(float2 a, float2 b, float2 c) {
    return make_float2(fmaf(a.x, b.x, c.x), fmaf(a.y, b.y, c.y));
}
__device__ __forceinline__ float2 fmas(float2 a, float s, float2 c) {
    return make_float2(fmaf(a.x, s, c.x), fmaf(a.y, s, c.y));
}

// ---------------------------------------------------------------------------
// Projection GEMM -> EXPONENTIATED, INTERLEAVED transposed output.
// (R12 version, known-good, ~13us by R17 budget calibration.)
// ---------------------------------------------------------------------------
__global__ __launch_bounds__(256) void proj_kernel(const float* __restrict__ queries,
                                                   const float* __restrict__ values,
                                                   const float* __restrict__ w1,
                                                   const float* __restrict__ w2,
                                                   float* __restrict__ pqI,
                                                   float* __restrict__ pvI,
                                                   float* __restrict__ denom) {
    __shared__ float smem[32 * 36 + 32 * 128];   // As[32][36] | Ws[32*128]; Ls aliases
    float (*As)[36] = (float(*)[36])smem;        // [k][row], stride 36 (16B-aligned rows)
    float* Ws = smem + 32 * 36;                  // [k][u]
    float (*Ls)[36] = (float(*)[36])smem;        // [u][row], epilogue (after barrier)

    const int bid = blockIdx.x;
    const int tid = threadIdx.x;
    if (bid == 0) *(float4*)&denom[tid * 4] = make_float4(0.f, 0.f, 0.f, 0.f);

    const bool isv = (bid < 256);
    const float* A; const float* W; int b, r0, ROWS; float* Ob;
    if (isv) {                             // values: 8192 rows, 64 blocks/batch
        b = bid >> 6; r0 = (bid & 63) * 32;
        A = values + ((size_t)(b * VV + r0)) * HH;  W = w2;
        Ob = pvI + (size_t)b * UU * VV;  ROWS = VV;
    } else {                               // queries: 1024 rows, 8 blocks/batch
        const int q = bid - 256;
        b = q >> 3; r0 = (q & 7) * 32;
        A = queries + ((size_t)(b * QQ + r0)) * HH; W = w1;
        Ob = pqI + (size_t)b * UU * QQ;  ROWS = QQ;
    }

    const int tx = tid & 31;         // u-group: u = tx*4 .. tx*4+3
    const int ty = tid >> 5;         // row-quad: rows 4ty .. 4ty+3
    float4 acc[4];
#pragma unroll
    for (int j = 0; j < 4; j++) acc[j] = make_float4(0.f, 0.f, 0.f, 0.f);

    for (int k0 = 0; k0 < HH; k0 += 32) {
        {   // A tile: 32 rows x 32 k, transposed store; one float4 per thread
            const int r = tid >> 3, kk4 = (tid & 7) * 4;
            const float4 a = *(const float4*)&A[(size_t)r * HH + k0 + kk4];
            As[kk4 + 0][r] = a.x; As[kk4 + 1][r] = a.y;
            As[kk4 + 2][r] = a.z; As[kk4 + 3][r] = a.w;
        }
#pragma unroll
        for (int t = 0; t < 4; t++) {  // W tile: 32 k x 128 u
            const int f = tid + t * 256;
            const int kk = f >> 5, u4 = (f & 31) * 4;
            *(float4*)&Ws[kk * 128 + u4] = *(const float4*)&W[(size_t)(k0 + kk) * UU + u4];
        }
        __syncthreads();
#pragma unroll
        for (int kk = 0; kk < 32; kk++) {
            const float4 a = *(const float4*)&As[kk][ty * 4];       // 4 rows
            const float4 w = *(const float4*)&Ws[kk * 128 + tx * 4];
            fma4(acc[0], a.x, w);
            fma4(acc[1], a.y, w);
            fma4(acc[2], a.z, w);
            fma4(acc[3], a.w, w);
        }
        __syncthreads();
    }
    // epilogue: exp2 + transpose via Ls (aliases As/Ws — barrier passed above)
#pragma unroll
    for (int j = 0; j < 4; j++) {
        const float aa[4] = {acc[j].x, acc[j].y, acc[j].z, acc[j].w};
#pragma unroll
        for (int i = 0; i < 4; i++)
            Ls[tx * 4 + i][ty * 4 + j] = __builtin_amdgcn_exp2f(aa[i] * C2E);
    }
    __syncthreads();
#pragma unroll
    for (int t = 0; t < 4; t++) {    // 1024 float4 chunks: (g = idx>>5, r = idx&31)
        const int idx = tid + t * 256;
        const int g = idx >> 5, r = idx & 31;
        float4 o;
        o.x = Ls[4 * g + 0][r]; o.y = Ls[4 * g + 1][r];
        o.z = Ls[4 * g + 2][r]; o.w = Ls[4 * g + 3][r];
        *(float4*)&Ob[((size_t)g * ROWS + r0 + r) * 4] = o;
    }
}

// ---------------------------------------------------------------------------
// R22 fused: R18 champion structure with Phase A remapped from
// (512 v x 2 uh) to (256 vpairs x 2 qh x 2 uh): each thread computes TWO
// v's (v, v+256) per e0/e1 LDS read -> per-CU Phase-A ds_read_b128 count
// halves (4096 -> 2048 wave-instrs through the single per-CU LDS unit).
// THEORY (last surviving): Phase A is LDS-issue-pipe bound: 4096 broadcast
// reads x ~12cy ~= 20us serialized at one shared unit -> doesn't scale with
// waves (R11/R12 nulls), shows no bank conflicts (uniform), caps VALUBusy
// at ~60%. Per-(q,v) math bit-identical (same u-grouping, same g order);
// ev global stream doubles (L2-resident, cheap). Phase B byte-identical.
// ---------------------------------------------------------------------------
__global__ __launch_bounds__(1024, 4) void fused_kernel(const float* __restrict__ pqI,
                                                        const float* __restrict__ pvI,
                                                        const float* __restrict__ vvec,
                                                        const float* __restrict__ values,
                                                        float* __restrict__ slab,
                                                        float* __restrict__ denom) {
    __shared__ float att[512][20];        // [v][q] padded; persists A->B
    __shared__ float scratch[24 * 512];   // 48KB: A-combine cbuf [16][512] / B-scratch [24][512]
    __shared__ float wred[8][8];
    __shared__ float eqs[32 * 64];        // 8KB: Eq tile [G][16q x 4u]
    const int tid = threadIdx.x;
    const int bid = blockIdx.x;
    const int vs = bid & 3, qb = (bid >> 2) & 15, b = bid >> 6;
    const int qbase = qb * 16, vbase = vs * 512;

    // ---- Phase A ----
    const int vpair = tid & 255;          // v = vbase+vpair and vbase+vpair+256
    const int qh = (tid >> 8) & 1;        // wave-uniform q-half (8 q)
    const int uh = tid >> 9;              // wave-uniform u-half

    const float* pq4 = pqI + (size_t)b * UU * QQ + (size_t)qbase * 4;  // Eq block (16q x 4u per G)

    // stage Eq tile: 512 float4 (64B per G, contiguous), coalesced
    if (tid < 512) {
        const int G = tid >> 4, f4 = tid & 15;
        *(float4*)&eqs[G * 64 + f4 * 4] = *(const float4*)&pq4[(size_t)G * QQ * 4 + f4 * 4];
    }

    float vsum = 0.0f;
#pragma unroll
    for (int u4 = 0; u4 < UU; u4 += 4) {
        const float4 t = *(const float4*)&vvec[u4];
        vsum += t.x + t.y + t.z + t.w;
    }

    const float* pvA = pvI + (size_t)b * UU * VV + (size_t)(vbase + vpair) * 4;  // Ev, v
    const float* pvB = pvA + 256 * 4;                                            // Ev, v+256

    float2 acc0[4], acc1[4];              // [p] for v and v+256
#pragma unroll
    for (int p = 0; p < 4; p++) { acc0[p] = make_float2(0.f, 0.f); acc1[p] = make_float2(0.f, 0.f); }

    const int G0 = uh * 16;
    float4 eva = *(const float4*)&pvA[(size_t)G0 * VV * 4];   // prefetch g=0
    float4 evb = *(const float4*)&pvB[(size_t)G0 * VV * 4];
    __syncthreads();   // Eq staged

    for (int g = 0; g < 16; g++) {
        const int G = G0 + g;
        const float* eqp = &eqs[G * 64 + qh * 32];    // LDS, wave-uniform -> broadcast
        float4 evan, evbn;
        if (g < 15) {
            evan = *(const float4*)&pvA[(size_t)(G + 1) * VV * 4];
            evbn = *(const float4*)&pvB[(size_t)(G + 1) * VV * 4];
        }
        const float4 wq = *(const float4*)&vvec[G * 4];
        const float w0 = 2.f * wq.x, w1 = 2.f * wq.y;
        const float w2 = 2.f * wq.z, w3 = 2.f * wq.w;
#pragma unroll
        for (int p = 0; p < 4; p++) {
            const float4 e0 = *(const float4*)&eqp[(2 * p) * 4];      // q=qh*8+2p (ds_read_b128)
            const float4 e1 = *(const float4*)&eqp[(2 * p + 1) * 4];  // q=qh*8+2p+1
            {   // v (eva)
                const float2 a1 = make_float2(fmaf(e0.x, eva.x, 1.f), fmaf(e1.x, eva.x, 1.f));
                const float2 b1 = make_float2(fmaf(e0.y, eva.y, 1.f), fmaf(e1.y, eva.y, 1.f));
                const float2 c1 = make_float2(fmaf(e0.z, eva.z, 1.f), fmaf(e1.z, eva.z, 1.f));
                const float2 d1 = make_float2(fmaf(e0.w, eva.w, 1.f), fmaf(e1.w, eva.w, 1.f));
                const float2 pab = mul2(a1, b1), pcd = mul2(c1, d1);
                const float2 nab = fmas(a1, w1, muls(b1, w0));   // w0*b1 + w1*a1
                const float2 ncd = fmas(c1, w3, muls(d1, w2));
                const float2 num = fma2(nab, pcd, mul2(ncd, pab));
                const float2 den = mul2(pab, pcd);
                acc0[p] = fma2(num, rcp2(den), acc0[p]);
            }
            {   // v+256 (evb)
                const float2 a1 = make_float2(fmaf(e0.x, evb.x, 1.f), fmaf(e1.x, evb.x, 1.f));
                const float2 b1 = make_float2(fmaf(e0.y, evb.y, 1.f), fmaf(e1.y, evb.y, 1.f));
                const float2 c1 = make_float2(fmaf(e0.z, evb.z, 1.f), fmaf(e1.z, evb.z, 1.f));
                const float2 d1 = make_float2(fmaf(e0.w, evb.w, 1.f), fmaf(e1.w, evb.w, 1.f));
                const float2 pab = mul2(a1, b1), pcd = mul2(c1, d1);
                const float2 nab = fmas(a1, w1, muls(b1, w0));
                const float2 ncd = fmas(c1, w3, muls(d1, w2));
                const float2 num = fma2(nab, pcd, mul2(ncd, pab));
                const float2 den = mul2(pab, pcd);
                acc1[p] = fma2(num, rcp2(den), acc1[p]);
            }
        }
        eva = evan; evb = evbn;
    }

    // combine u-halves via cbuf[q][v] (q-major, lane-consecutive b32)
    float* cb = scratch;   // [16 q][512 v]
    if (uh == 1) {
#pragma unroll
        for (int p = 0; p < 4; p++) {
            cb[(qh * 8 + 2 * p + 0) * 512 + vpair]       = acc0[p].x;
            cb[(qh * 8 + 2 * p + 1) * 512 + vpair]       = acc0[p].y;
            cb[(qh * 8 + 2 * p + 0) * 512 + 256 + vpair] = acc1[p].x;
            cb[(qh * 8 + 2 * p + 1) * 512 + 256 + vpair] = acc1[p].y;
        }
    }
    __syncthreads();
    if (uh == 0) {
#pragma unroll
        for (int p = 0; p < 4; p++) {
            const float hx0 = cb[(qh * 8 + 2 * p + 0) * 512 + vpair];
            const float hy0 = cb[(qh * 8 + 2 * p + 1) * 512 + vpair];
            float2 e0v;
            e0v.x = __builtin_amdgcn_exp2f((vsum - (acc0[p].x + hx0)) * LOG2E);
            e0v.y = __builtin_amdgcn_exp2f((vsum - (acc0[p].y + hy0)) * LOG2E);
            *(float2*)&att[vpair][qh * 8 + 2 * p] = e0v;
            acc0[p] = e0v;
            const float hx1 = cb[(qh * 8 + 2 * p + 0) * 512 + 256 + vpair];
            const float hy1 = cb[(qh * 8 + 2 * p + 1) * 512 + 256 + vpair];
            float2 e1v;
            e1v.x = __builtin_amdgcn_exp2f((vsum - (acc1[p].x + hx1)) * LOG2E);
            e1v.y = __builtin_amdgcn_exp2f((vsum - (acc1[p].y + hy1)) * LOG2E);
            *(float2*)&att[256 + vpair][qh * 8 + 2 * p] = e1v;
            acc1[p] = e1v;
        }
        // denom partials: combine the 2 v's, then butterfly over the wave's 64 lanes
        float2 s[4];
#pragma unroll
        for (int p = 0; p < 4; p++) {
            s[p].x = acc0[p].x + acc1[p].x;
            s[p].y = acc0[p].y + acc1[p].y;
        }
#pragma unroll
        for (int off = 1; off < 64; off <<= 1) {
#pragma unroll
            for (int p = 0; p < 4; p++) {
                s[p].x += __shfl_xor(s[p].x, off, 64);
                s[p].y += __shfl_xor(s[p].y, off, 64);
            }
        }
        if ((tid & 63) == 0) {
            const int w = tid >> 6;   // 0..7 (uh=0 waves; w<4 -> qh0, w>=4 -> qh1)
#pragma unroll
            for (int p = 0; p < 4; p++) {
                wred[w][2 * p + 0] = s[p].x;
                wred[w][2 * p + 1] = s[p].y;
            }
        }
    }
    __syncthreads();
    if (tid < 16) {
        const int qh2 = tid >> 3, qq = tid & 7;
        atomicAdd(&denom[b * QQ + qbase + tid],
                  wred[qh2 * 4 + 0][qq] + wred[qh2 * 4 + 1][qq] +
                  wred[qh2 * 4 + 2][qq] + wred[qh2 * 4 + 3][qq]);
    }

    // ---- Phase B: (qh: 8 q, vh: 4 v-quarters of 128) across 8 half-waves ----
    const int hg = tid & 127, sel = tid >> 7;       // sel wave-uniform
    const int qhb = sel & 1, vh = sel >> 1;         // vh 0..3
    const int h0 = hg * 4;
    const float* vp = values + ((size_t)(b * VV + vbase + vh * 128)) * HH + h0;

    float4 oacc[8];
#pragma unroll
    for (int j = 0; j < 8; j++) oacc[j] = make_float4(0.f, 0.f, 0.f, 0.f);

#pragma unroll 2
    for (int vv = 0; vv < 128; vv++) {
        const float4 w = *(const float4*)&vp[(size_t)vv * HH];
        const float4 a0 = *(const float4*)&att[vh * 128 + vv][qhb * 8 + 0];  // broadcast
        const float4 a1 = *(const float4*)&att[vh * 128 + vv][qhb * 8 + 4];
        fma4(oacc[0], a0.x, w); fma4(oacc[1], a0.y, w);
        fma4(oacc[2], a0.z, w); fma4(oacc[3], a0.w, w);
        fma4(oacc[4], a1.x, w); fma4(oacc[5], a1.y, w);
        fma4(oacc[6], a1.z, w); fma4(oacc[7], a1.w, w);
    }

    // epilogue: 2 rounds over qh; vh 1..3 stage to 3 LDS buffers, vh 0 sums+stores
    float (*scr)[512] = (float(*)[512])scratch;   // 24 rows x 512
    for (int rr = 0; rr < 2; rr++) {
        __syncthreads();
        if (qhb == rr && vh > 0) {
#pragma unroll
            for (int j = 0; j < 8; j++)
                *(float4*)&scr[(vh - 1) * 8 + j][h0] = oacc[j];
        }
        __syncthreads();
        if (qhb == rr && vh == 0) {
            float* sp = slab + (size_t)vs * (BB * QQ * HH);
#pragma unroll
            for (int j = 0; j < 8; j++) {
                const float4 p0 = *(const float4*)&scr[0 * 8 + j][h0];
                const float4 p1 = *(const float4*)&scr[1 * 8 + j][h0];
                const float4 p2 = *(const float4*)&scr[2 * 8 + j][h0];
                float4 o;
                o.x = oacc[j].x + p0.x + p1.x + p2.x;
                o.y = oacc[j].y + p0.y + p1.y + p2.y;
                o.z = oacc[j].z + p0.z + p1.z + p2.z;
                o.w = oacc[j].w + p0.w + p1.w + p2.w;
                *(float4*)&sp[((size_t)(b * QQ + qbase + rr * 8 + j)) * HH + h0] = o;
            }
        }
    }
}

// ---------------------------------------------------------------------------
// out = (sum of 4 slabs) * rcp(denom[row]). 131072 float4s, grid 512.
// ---------------------------------------------------------------------------
__global__ __launch_bounds__(256) void reduce_kernel(const float* __restrict__ slab,
                                                     const float* __restrict__ denom,
                                                     float* __restrict__ out) {
    const int i = blockIdx.x * 256 + threadIdx.x;    // float4 index
    const float r = __builtin_amdgcn_rcpf(denom[i >> 7]);
    const float4* s4 = (const float4*)slab;
    float4 s = s4[i];
#pragma unroll
    for (int k = 1; k < 4; k++) {
        const float4 p = s4[(size_t)k * (BB * QQ * HH / 4) + i];
        s.x += p.x; s.y += p.y; s.z += p.z; s.w += p.w;
    }
    s.x *= r; s.y *= r; s.z *= r; s.w *= r;
    ((float4*)out)[i] = s;
}

// ---------------------------------------------------------------------------
extern "C" void kernel_launch(void* const* d_in, const int* in_sizes, int n_in,
                              void* d_out, int out_size, void* d_ws, size_t ws_size,
                              hipStream_t stream) {
    const float* queries = (const float*)d_in[0];  // [B,Q,H]
    const float* values  = (const float*)d_in[1];  // [B,V,H]
    const float* w1      = (const float*)d_in[2];  // [H,U]
    const float* w2      = (const float*)d_in[3];  // [H,U]
    const float* vvec    = (const float*)d_in[4];  // [U]
    float* out = (float*)d_out;

    // ws (floats): pqI[131072] | pvI[1048576] | denom[1024] | slab[4*524288]
    float* ws    = (float*)d_ws;
    float* pqI   = ws;
    float* pvI   = pqI + BB * UU * QQ;
    float* denom = pvI + (size_t)BB * UU * VV;
    float* slab  = denom + BB * QQ;

    proj_kernel<<<256 + 32, 256, 0, stream>>>(queries, values, w1, w2, pqI, pvI, denom);
    fused_kernel<<<BB * (QQ / 16) * (VV / 512), 1024, 0, stream>>>(pqI, pvI, vvec, values, slab, denom);
    reduce_kernel<<<(BB * QQ * HH) / 4 / 256, 256, 0, stream>>>(slab, denom, out);
}

// Round 16
// 162.830 us; speedup vs baseline: 1.0450x; 1.0293x over previous
//
#include <hip/hip_runtime.h>

#define BB 4
#define QQ 256
#define VV 2048
#define HH 512
#define UU 128

// tanh arg scale folded into projections: C2E = 2*log2(e); exp(x)=exp2(x*LOG2E)
#define C2E   2.8853900817779268f
#define LOG2E 1.4426950408889634f

__device__ __forceinline__ void fma4(float4& a, float s, const float4& w) {
    a.x = fmaf(s, w.x, a.x);
    a.y = fmaf(s, w.y, a.y);
    a.z = fmaf(s, w.z, a.z);
    a.w = fmaf(s, w.w, a.w);
}
__device__ __forceinline__ float2 rcp2(float2 x) {
    return make_float2(__builtin_amdgcn_rcpf(x.x), __builtin_amdgcn_rcpf(x.y));
}
__device__ __forceinline__ float2 mul2(float2 a, float2 b) { return make_float2(a.x*b.x, a.y*b.y); }
__device__ __forceinline__ float2 muls(float2 a, float s)  { return make_float2(a.x*s, a.y*s); }
__device__ __forceinline__ float2 fma2(float2 a, float2 b, float2 c) {
    return make_float2(fmaf(a.x, b.x, c.x), fmaf(a.y, b.y, c.y));
}
__device__ __forceinline__ float2 fmas(float2 a, float s, float2 c) {
    return make_float2(fmaf(a.x, s, c.x), fmaf(a.y, s, c.y));
}

// ---------------------------------------------------------------------------
// Projection GEMM -> EXPONENTIATED, INTERLEAVED transposed output.
// (R12 version, known-good, ~13us by R17 budget calibration.)
// ---------------------------------------------------------------------------
__global__ __launch_bounds__(256) void proj_kernel(const float* __restrict__ queries,
                                                   const float* __restrict__ values,
                                                   const float* __restrict__ w1,
                                                   const float* __restrict__ w2,
                                                   float* __restrict__ pqI,
                                                   float* __restrict__ pvI,
                                                   float* __restrict__ denom) {
    __shared__ float smem[32 * 36 + 32 * 128];   // As[32][36] | Ws[32*128]; Ls aliases
    float (*As)[36] = (float(*)[36])smem;        // [k][row], stride 36 (16B-aligned rows)
    float* Ws = smem + 32 * 36;                  // [k][u]
    float (*Ls)[36] = (float(*)[36])smem;        // [u][row], epilogue (after barrier)

    const int bid = blockIdx.x;
    const int tid = threadIdx.x;
    if (bid == 0) *(float4*)&denom[tid * 4] = make_float4(0.f, 0.f, 0.f, 0.f);

    const bool isv = (bid < 256);
    const float* A; const float* W; int b, r0, ROWS; float* Ob;
    if (isv) {                             // values: 8192 rows, 64 blocks/batch
        b = bid >> 6; r0 = (bid & 63) * 32;
        A = values + ((size_t)(b * VV + r0)) * HH;  W = w2;
        Ob = pvI + (size_t)b * UU * VV;  ROWS = VV;
    } else {                               // queries: 1024 rows, 8 blocks/batch
        const int q = bid - 256;
        b = q >> 3; r0 = (q & 7) * 32;
        A = queries + ((size_t)(b * QQ + r0)) * HH; W = w1;
        Ob = pqI + (size_t)b * UU * QQ;  ROWS = QQ;
    }

    const int tx = tid & 31;         // u-group: u = tx*4 .. tx*4+3
    const int ty = tid >> 5;         // row-quad: rows 4ty .. 4ty+3
    float4 acc[4];
#pragma unroll
    for (int j = 0; j < 4; j++) acc[j] = make_float4(0.f, 0.f, 0.f, 0.f);

    for (int k0 = 0; k0 < HH; k0 += 32) {
        {   // A tile: 32 rows x 32 k, transposed store; one float4 per thread
            const int r = tid >> 3, kk4 = (tid & 7) * 4;
            const float4 a = *(const float4*)&A[(size_t)r * HH + k0 + kk4];
            As[kk4 + 0][r] = a.x; As[kk4 + 1][r] = a.y;
            As[kk4 + 2][r] = a.z; As[kk4 + 3][r] = a.w;
        }
#pragma unroll
        for (int t = 0; t < 4; t++) {  // W tile: 32 k x 128 u
            const int f = tid + t * 256;
            const int kk = f >> 5, u4 = (f & 31) * 4;
            *(float4*)&Ws[kk * 128 + u4] = *(const float4*)&W[(size_t)(k0 + kk) * UU + u4];
        }
        __syncthreads();
#pragma unroll
        for (int kk = 0; kk < 32; kk++) {
            const float4 a = *(const float4*)&As[kk][ty * 4];       // 4 rows
            const float4 w = *(const float4*)&Ws[kk * 128 + tx * 4];
            fma4(acc[0], a.x, w);
            fma4(acc[1], a.y, w);
            fma4(acc[2], a.z, w);
            fma4(acc[3], a.w, w);
        }
        __syncthreads();
    }
    // epilogue: exp2 + transpose via Ls (aliases As/Ws — barrier passed above)
#pragma unroll
    for (int j = 0; j < 4; j++) {
        const float aa[4] = {acc[j].x, acc[j].y, acc[j].z, acc[j].w};
#pragma unroll
        for (int i = 0; i < 4; i++)
            Ls[tx * 4 + i][ty * 4 + j] = __builtin_amdgcn_exp2f(aa[i] * C2E);
    }
    __syncthreads();
#pragma unroll
    for (int t = 0; t < 4; t++) {    // 1024 float4 chunks: (g = idx>>5, r = idx&31)
        const int idx = tid + t * 256;
        const int g = idx >> 5, r = idx & 31;
        float4 o;
        o.x = Ls[4 * g + 0][r]; o.y = Ls[4 * g + 1][r];
        o.z = Ls[4 * g + 2][r]; o.w = Ls[4 * g + 3][r];
        *(float4*)&Ob[((size_t)g * ROWS + r0 + r) * 4] = o;
    }
}

// ---------------------------------------------------------------------------
// R23 fused: continuation of the CONFIRMED LDS-issue-pipe lever (R18 -5.2us,
// R22 -3.8us). Phase A remapped from (256 vpairs x 2 qh x 2 uh) to
// (128 vgroups x 4 v-offsets x 4 qq x 2 uh): each thread computes FOUR v's
// (v, v+128, v+256, v+384) for 4 q's per e0/e1 read -> per-CU Phase-A
// ds_read_b128 count halves again (2048 -> 1024 wave-instrs).
// Cost: ev global stream x2 vs R22 (each (v,G) read by 4 qq groups) --
// L2-resident, hidden across 4 streams. Per-(q,v) math bit-identical.
// Phase B byte-identical.
// ---------------------------------------------------------------------------
__global__ __launch_bounds__(1024, 4) void fused_kernel(const float* __restrict__ pqI,
                                                        const float* __restrict__ pvI,
                                                        const float* __restrict__ vvec,
                                                        const float* __restrict__ values,
                                                        float* __restrict__ slab,
                                                        float* __restrict__ denom) {
    __shared__ float att[512][20];        // [v][q] padded; persists A->B
    __shared__ float scratch[24 * 512];   // 48KB: A-combine cbuf [16][512] / B-scratch [24][512]
    __shared__ float wred[8][8];
    __shared__ float eqs[32 * 64];        // 8KB: Eq tile [G][16q x 4u]
    const int tid = threadIdx.x;
    const int bid = blockIdx.x;
    const int vs = bid & 3, qb = (bid >> 2) & 15, b = bid >> 6;
    const int qbase = qb * 16, vbase = vs * 512;

    // ---- Phase A ----
    const int vgrp = tid & 127;           // v = vbase + vgrp + k*128, k=0..3
    const int qq = (tid >> 7) & 3;        // wave-uniform q-quad (4 q)
    const int uh = tid >> 9;              // wave-uniform u-half

    const float* pq4 = pqI + (size_t)b * UU * QQ + (size_t)qbase * 4;  // Eq block (16q x 4u per G)

    // stage Eq tile: 512 float4 (64B per G, contiguous), coalesced
    if (tid < 512) {
        const int G = tid >> 4, f4 = tid & 15;
        *(float4*)&eqs[G * 64 + f4 * 4] = *(const float4*)&pq4[(size_t)G * QQ * 4 + f4 * 4];
    }

    float vsum = 0.0f;
#pragma unroll
    for (int u4 = 0; u4 < UU; u4 += 4) {
        const float4 t = *(const float4*)&vvec[u4];
        vsum += t.x + t.y + t.z + t.w;
    }

    const float* pvb = pvI + (size_t)b * UU * VV + (size_t)(vbase + vgrp) * 4;  // Ev streams

    float2 acc[4][2];                     // [k][p]
#pragma unroll
    for (int k = 0; k < 4; k++) { acc[k][0] = make_float2(0.f, 0.f); acc[k][1] = make_float2(0.f, 0.f); }

    const int G0 = uh * 16;
    float4 ev[4], evn[4];
#pragma unroll
    for (int k = 0; k < 4; k++)           // prefetch g=0, 4 streams
        ev[k] = *(const float4*)&pvb[(size_t)G0 * VV * 4 + k * 128 * 4];
    __syncthreads();   // Eq staged

    for (int g = 0; g < 16; g++) {
        const int G = G0 + g;
        const float* eqp = &eqs[G * 64 + qq * 16];    // LDS, wave-uniform -> broadcast
        if (g < 15) {
#pragma unroll
            for (int k = 0; k < 4; k++)
                evn[k] = *(const float4*)&pvb[(size_t)(G + 1) * VV * 4 + k * 128 * 4];
        }
        const float4 wq = *(const float4*)&vvec[G * 4];
        const float w0 = 2.f * wq.x, w1 = 2.f * wq.y;
        const float w2 = 2.f * wq.z, w3 = 2.f * wq.w;
#pragma unroll
        for (int p = 0; p < 2; p++) {
            const float4 e0 = *(const float4*)&eqp[(2 * p) * 4];      // q=qq*4+2p (ds_read_b128)
            const float4 e1 = *(const float4*)&eqp[(2 * p + 1) * 4];  // q=qq*4+2p+1
#pragma unroll
            for (int k = 0; k < 4; k++) {
                const float2 a1 = make_float2(fmaf(e0.x, ev[k].x, 1.f), fmaf(e1.x, ev[k].x, 1.f));
                const float2 b1 = make_float2(fmaf(e0.y, ev[k].y, 1.f), fmaf(e1.y, ev[k].y, 1.f));
                const float2 c1 = make_float2(fmaf(e0.z, ev[k].z, 1.f), fmaf(e1.z, ev[k].z, 1.f));
                const float2 d1 = make_float2(fmaf(e0.w, ev[k].w, 1.f), fmaf(e1.w, ev[k].w, 1.f));
                const float2 pab = mul2(a1, b1), pcd = mul2(c1, d1);
                const float2 nab = fmas(a1, w1, muls(b1, w0));   // w0*b1 + w1*a1
                const float2 ncd = fmas(c1, w3, muls(d1, w2));
                const float2 num = fma2(nab, pcd, mul2(ncd, pab));
                const float2 den = mul2(pab, pcd);
                acc[k][p] = fma2(num, rcp2(den), acc[k][p]);
            }
        }
#pragma unroll
        for (int k = 0; k < 4; k++) ev[k] = evn[k];
    }

    // combine u-halves via cbuf[q][v] (q-major, lane-consecutive b32)
    float* cb = scratch;   // [16 q][512 v]
    if (uh == 1) {
#pragma unroll
        for (int p = 0; p < 2; p++)
#pragma unroll
            for (int k = 0; k < 4; k++) {
                cb[(qq * 4 + 2 * p + 0) * 512 + vgrp + k * 128] = acc[k][p].x;
                cb[(qq * 4 + 2 * p + 1) * 512 + vgrp + k * 128] = acc[k][p].y;
            }
    }
    __syncthreads();
    if (uh == 0) {
#pragma unroll
        for (int p = 0; p < 2; p++)
#pragma unroll
            for (int k = 0; k < 4; k++) {
                const float hx = cb[(qq * 4 + 2 * p + 0) * 512 + vgrp + k * 128];
                const float hy = cb[(qq * 4 + 2 * p + 1) * 512 + vgrp + k * 128];
                float2 e;
                e.x = __builtin_amdgcn_exp2f((vsum - (acc[k][p].x + hx)) * LOG2E);
                e.y = __builtin_amdgcn_exp2f((vsum - (acc[k][p].y + hy)) * LOG2E);
                *(float2*)&att[vgrp + k * 128][qq * 4 + 2 * p] = e;
                acc[k][p] = e;
            }
        // denom partials: combine the 4 v-offsets, then butterfly over 64 lanes
        float2 s[2];
#pragma unroll
        for (int p = 0; p < 2; p++) {
            s[p].x = acc[0][p].x + acc[1][p].x + acc[2][p].x + acc[3][p].x;
            s[p].y = acc[0][p].y + acc[1][p].y + acc[2][p].y + acc[3][p].y;
        }
#pragma unroll
        for (int off = 1; off < 64; off <<= 1) {
#pragma unroll
            for (int p = 0; p < 2; p++) {
                s[p].x += __shfl_xor(s[p].x, off, 64);
                s[p].y += __shfl_xor(s[p].y, off, 64);
            }
        }
        if ((tid & 63) == 0) {
            const int w = tid >> 6;   // 0..7 (uh=0): waves (2m,2m+1) share qq=m
#pragma unroll
            for (int p = 0; p < 2; p++) {
                wred[w][2 * p + 0] = s[p].x;
                wred[w][2 * p + 1] = s[p].y;
            }
        }
    }
    __syncthreads();
    if (tid < 16) {
        const int qq2 = tid >> 2, j = tid & 3;   // q = qq2*4 + j
        atomicAdd(&denom[b * QQ + qbase + tid],
                  wred[2 * qq2][j] + wred[2 * qq2 + 1][j]);
    }

    // ---- Phase B: (qh: 8 q, vh: 4 v-quarters of 128) across 8 half-waves ----
    const int hg = tid & 127, sel = tid >> 7;       // sel wave-uniform
    const int qhb = sel & 1, vh = sel >> 1;         // vh 0..3
    const int h0 = hg * 4;
    const float* vp = values + ((size_t)(b * VV + vbase + vh * 128)) * HH + h0;

    float4 oacc[8];
#pragma unroll
    for (int j = 0; j < 8; j++) oacc[j] = make_float4(0.f, 0.f, 0.f, 0.f);

#pragma unroll 2
    for (int vv = 0; vv < 128; vv++) {
        const float4 w = *(const float4*)&vp[(size_t)vv * HH];
        const float4 a0 = *(const float4*)&att[vh * 128 + vv][qhb * 8 + 0];  // broadcast
        const float4 a1 = *(const float4*)&att[vh * 128 + vv][qhb * 8 + 4];
        fma4(oacc[0], a0.x, w); fma4(oacc[1], a0.y, w);
        fma4(oacc[2], a0.z, w); fma4(oacc[3], a0.w, w);
        fma4(oacc[4], a1.x, w); fma4(oacc[5], a1.y, w);
        fma4(oacc[6], a1.z, w); fma4(oacc[7], a1.w, w);
    }

    // epilogue: 2 rounds over qh; vh 1..3 stage to 3 LDS buffers, vh 0 sums+stores
    float (*scr)[512] = (float(*)[512])scratch;   // 24 rows x 512
    for (int rr = 0; rr < 2; rr++) {
        __syncthreads();
        if (qhb == rr && vh > 0) {
#pragma unroll
            for (int j = 0; j < 8; j++)
                *(float4*)&scr[(vh - 1) * 8 + j][h0] = oacc[j];
        }
        __syncthreads();
        if (qhb == rr && vh == 0) {
            float* sp = slab + (size_t)vs * (BB * QQ * HH);
#pragma unroll
            for (int j = 0; j < 8; j++) {
                const float4 p0 = *(const float4*)&scr[0 * 8 + j][h0];
                const float4 p1 = *(const float4*)&scr[1 * 8 + j][h0];
                const float4 p2 = *(const float4*)&scr[2 * 8 + j][h0];
                float4 o;
                o.x = oacc[j].x + p0.x + p1.x + p2.x;
                o.y = oacc[j].y + p0.y + p1.y + p2.y;
                o.z = oacc[j].z + p0.z + p1.z + p2.z;
                o.w = oacc[j].w + p0.w + p1.w + p2.w;
                *(float4*)&sp[((size_t)(b * QQ + qbase + rr * 8 + j)) * HH + h0] = o;
            }
        }
    }
}

// ---------------------------------------------------------------------------
// out = (sum of 4 slabs) * rcp(denom[row]). 131072 float4s, grid 512.
// ---------------------------------------------------------------------------
__global__ __launch_bounds__(256) void reduce_kernel(const float* __restrict__ slab,
                                                     const float* __restrict__ denom,
                                                     float* __restrict__ out) {
    const int i = blockIdx.x * 256 + threadIdx.x;    // float4 index
    const float r = __builtin_amdgcn_rcpf(denom[i >> 7]);
    const float4* s4 = (const float4*)slab;
    float4 s = s4[i];
#pragma unroll
    for (int k = 1; k < 4; k++) {
        const float4 p = s4[(size_t)k * (BB * QQ * HH / 4) + i];
        s.x += p.x; s.y += p.y; s.z += p.z; s.w += p.w;
    }
    s.x *= r; s.y *= r; s.z *= r; s.w *= r;
    ((float4*)out)[i] = s;
}

// ---------------------------------------------------------------------------
extern "C" void kernel_launch(void* const* d_in, const int* in_sizes, int n_in,
                              void* d_out, int out_size, void* d_ws, size_t ws_size,
                              hipStream_t stream) {
    const float* queries = (const float*)d_in[0];  // [B,Q,H]
    const float* values  = (const float*)d_in[1];  // [B,V,H]
    const float* w1      = (const float*)d_in[2];  // [H,U]
    const float* w2      = (const float*)d_in[3];  // [H,U]
    const float* vvec    = (const float*)d_in[4];  // [U]
    float* out = (float*)d_out;

    // ws (floats): pqI[131072] | pvI[1048576] | denom[1024] | slab[4*524288]
    float* ws    = (float*)d_ws;
    float* pqI   = ws;
    float* pvI   = pqI + BB * UU * QQ;
    float* denom = pvI + (size_t)BB * UU * VV;
    float* slab  = denom + BB * QQ;

    proj_kernel<<<256 + 32, 256, 0, stream>>>(queries, values, w1, w2, pqI, pvI, denom);
    fused_kernel<<<BB * (QQ / 16) * (VV / 512), 1024, 0, stream>>>(pqI, pvI, vvec, values, slab, denom);
    reduce_kernel<<<(BB * QQ * HH) / 4 / 256, 256, 0, stream>>>(slab, denom, out);
}

// Round 17
// 158.250 us; speedup vs baseline: 1.0752x; 1.0289x over previous
//
#include <hip/hip_runtime.h>

#define BB 4
#define QQ 256
#define VV 2048
#define HH 512
#define UU 128

// tanh arg scale folded into projections: C2E = 2*log2(e); exp(x)=exp2(x*LOG2E)
#define C2E   2.8853900817779268f
#define LOG2E 1.4426950408889634f

typedef float f32x2v __attribute__((ext_vector_type(2)));

__device__ __forceinline__ void fma4(float4& a, float s, const float4& w) {
    a.x = fmaf(s, w.x, a.x);
    a.y = fmaf(s, w.y, a.y);
    a.z = fmaf(s, w.z, a.z);
    a.w = fmaf(s, w.w, a.w);
}
__device__ __forceinline__ f32x2v bc2(float x) { return (f32x2v){x, x}; }

// ---------------------------------------------------------------------------
// Projection GEMM -> EXPONENTIATED, INTERLEAVED transposed output.
// (R12 version, known-good, ~13us by R17 budget calibration.)
// ---------------------------------------------------------------------------
__global__ __launch_bounds__(256) void proj_kernel(const float* __restrict__ queries,
                                                   const float* __restrict__ values,
                                                   const float* __restrict__ w1,
                                                   const float* __restrict__ w2,
                                                   float* __restrict__ pqI,
                                                   float* __restrict__ pvI,
                                                   float* __restrict__ denom) {
    __shared__ float smem[32 * 36 + 32 * 128];   // As[32][36] | Ws[32*128]; Ls aliases
    float (*As)[36] = (float(*)[36])smem;        // [k][row], stride 36 (16B-aligned rows)
    float* Ws = smem + 32 * 36;                  // [k][u]
    float (*Ls)[36] = (float(*)[36])smem;        // [u][row], epilogue (after barrier)

    const int bid = blockIdx.x;
    const int tid = threadIdx.x;
    if (bid == 0) *(float4*)&denom[tid * 4] = make_float4(0.f, 0.f, 0.f, 0.f);

    const bool isv = (bid < 256);
    const float* A; const float* W; int b, r0, ROWS; float* Ob;
    if (isv) {                             // values: 8192 rows, 64 blocks/batch
        b = bid >> 6; r0 = (bid & 63) * 32;
        A = values + ((size_t)(b * VV + r0)) * HH;  W = w2;
        Ob = pvI + (size_t)b * UU * VV;  ROWS = VV;
    } else {                               // queries: 1024 rows, 8 blocks/batch
        const int q = bid - 256;
        b = q >> 3; r0 = (q & 7) * 32;
        A = queries + ((size_t)(b * QQ + r0)) * HH; W = w1;
        Ob = pqI + (size_t)b * UU * QQ;  ROWS = QQ;
    }

    const int tx = tid & 31;         // u-group: u = tx*4 .. tx*4+3
    const int ty = tid >> 5;         // row-quad: rows 4ty .. 4ty+3
    float4 acc[4];
#pragma unroll
    for (int j = 0; j < 4; j++) acc[j] = make_float4(0.f, 0.f, 0.f, 0.f);

    for (int k0 = 0; k0 < HH; k0 += 32) {
        {   // A tile: 32 rows x 32 k, transposed store; one float4 per thread
            const int r = tid >> 3, kk4 = (tid & 7) * 4;
            const float4 a = *(const float4*)&A[(size_t)r * HH + k0 + kk4];
            As[kk4 + 0][r] = a.x; As[kk4 + 1][r] = a.y;
            As[kk4 + 2][r] = a.z; As[kk4 + 3][r] = a.w;
        }
#pragma unroll
        for (int t = 0; t < 4; t++) {  // W tile: 32 k x 128 u
            const int f = tid + t * 256;
            const int kk = f >> 5, u4 = (f & 31) * 4;
            *(float4*)&Ws[kk * 128 + u4] = *(const float4*)&W[(size_t)(k0 + kk) * UU + u4];
        }
        __syncthreads();
#pragma unroll
        for (int kk = 0; kk < 32; kk++) {
            const float4 a = *(const float4*)&As[kk][ty * 4];       // 4 rows
            const float4 w = *(const float4*)&Ws[kk * 128 + tx * 4];
            fma4(acc[0], a.x, w);
            fma4(acc[1], a.y, w);
            fma4(acc[2], a.z, w);
            fma4(acc[3], a.w, w);
        }
        __syncthreads();
    }
    // epilogue: exp2 + transpose via Ls (aliases As/Ws — barrier passed above)
#pragma unroll
    for (int j = 0; j < 4; j++) {
        const float aa[4] = {acc[j].x, acc[j].y, acc[j].z, acc[j].w};
#pragma unroll
        for (int i = 0; i < 4; i++)
            Ls[tx * 4 + i][ty * 4 + j] = __builtin_amdgcn_exp2f(aa[i] * C2E);
    }
    __syncthreads();
#pragma unroll
    for (int t = 0; t < 4; t++) {    // 1024 float4 chunks: (g = idx>>5, r = idx&31)
        const int idx = tid + t * 256;
        const int g = idx >> 5, r = idx & 31;
        float4 o;
        o.x = Ls[4 * g + 0][r]; o.y = Ls[4 * g + 1][r];
        o.z = Ls[4 * g + 2][r]; o.w = Ls[4 * g + 3][r];
        *(float4*)&Ob[((size_t)g * ROWS + r0 + r) * 4] = o;
    }
}

// ---------------------------------------------------------------------------
// R24 fused: PACKED-FP32 Phase A. Arithmetic model of R23's counters
// (VALUBusy 59% == unpacked-scalar instr count at 2cy/wave-instr) says the
// compiler is NOT emitting v_pk_fma_f32 for the make_float2+fmaf idiom.
// Changes: (1) eqs re-laid as [G][u][16 q] (transposed at staging) so each
// q-pair (2p,2p+1) is memory-adjacent; (2) Phase A body in ext_vector f32x2
// with __builtin_elementwise_fma -> backend can select v_pk_fma/v_pk_mul.
// Same q-pairing, same op order, IEEE fma: bit-identical results.
// Thread mapping = R23 (128 vgrp x 4 qq x 2 uh, 4 v-streams); e-reads are
// 4x b128 per g (one per u), wave-uniform broadcasts, conflict-free.
// Phase B byte-identical.
// ---------------------------------------------------------------------------
__global__ __launch_bounds__(1024, 4) void fused_kernel(const float* __restrict__ pqI,
                                                        const float* __restrict__ pvI,
                                                        const float* __restrict__ vvec,
                                                        const float* __restrict__ values,
                                                        float* __restrict__ slab,
                                                        float* __restrict__ denom) {
    __shared__ float att[512][20];        // [v][q] padded; persists A->B
    __shared__ float scratch[24 * 512];   // 48KB: A-combine cbuf [16][512] / B-scratch [24][512]
    __shared__ float wred[8][8];
    __shared__ float eqs[32 * 64];        // 8KB: Eq tile [G][4 u][16 q]
    const int tid = threadIdx.x;
    const int bid = blockIdx.x;
    const int vs = bid & 3, qb = (bid >> 2) & 15, b = bid >> 6;
    const int qbase = qb * 16, vbase = vs * 512;

    // ---- Phase A ----
    const int vgrp = tid & 127;           // v = vbase + vgrp + k*128, k=0..3
    const int qq = (tid >> 7) & 3;        // wave-uniform q-quad (4 q)
    const int uh = tid >> 9;              // wave-uniform u-half

    const float* pq4 = pqI + (size_t)b * UU * QQ + (size_t)qbase * 4;  // Eq block (16q x 4u per G)

    // stage Eq tile TRANSPOSED: eqs[G][u][q]; 512 coalesced b128 loads
    if (tid < 512) {
        const int G = tid >> 4, q = tid & 15;
        const float4 lq = *(const float4*)&pq4[(size_t)G * QQ * 4 + q * 4];
        eqs[(G * 4 + 0) * 16 + q] = lq.x;
        eqs[(G * 4 + 1) * 16 + q] = lq.y;
        eqs[(G * 4 + 2) * 16 + q] = lq.z;
        eqs[(G * 4 + 3) * 16 + q] = lq.w;
    }

    float vsum = 0.0f;
#pragma unroll
    for (int u4 = 0; u4 < UU; u4 += 4) {
        const float4 t = *(const float4*)&vvec[u4];
        vsum += t.x + t.y + t.z + t.w;
    }

    const float* pvb = pvI + (size_t)b * UU * VV + (size_t)(vbase + vgrp) * 4;  // Ev streams

    f32x2v acc[4][2];                     // [k][p]; [0]=even q, [1]=odd q
#pragma unroll
    for (int k = 0; k < 4; k++) { acc[k][0] = bc2(0.f); acc[k][1] = bc2(0.f); }

    const int G0 = uh * 16;
    float4 ev[4], evn[4];
#pragma unroll
    for (int k = 0; k < 4; k++)           // prefetch g=0, 4 streams
        ev[k] = *(const float4*)&pvb[(size_t)G0 * VV * 4 + k * 128 * 4];
    __syncthreads();   // Eq staged

    const f32x2v one = bc2(1.f);
    for (int g = 0; g < 16; g++) {
        const int G = G0 + g;
        // e-tile: 4 uniform b128 reads (one per u), 4 q's each -> 2 q-pairs
        f32x2v ep[4][2];
#pragma unroll
        for (int u = 0; u < 4; u++) {
            const float4 equ = *(const float4*)&eqs[(G * 4 + u) * 16 + qq * 4];
            ep[u][0] = (f32x2v){equ.x, equ.y};   // q = qq*4+0, qq*4+1
            ep[u][1] = (f32x2v){equ.z, equ.w};   // q = qq*4+2, qq*4+3
        }
        if (g < 15) {
#pragma unroll
            for (int k = 0; k < 4; k++)
                evn[k] = *(const float4*)&pvb[(size_t)(G + 1) * VV * 4 + k * 128 * 4];
        }
        const float4 wq = *(const float4*)&vvec[G * 4];
        const f32x2v w0p = bc2(2.f * wq.x), w1p = bc2(2.f * wq.y);
        const f32x2v w2p = bc2(2.f * wq.z), w3p = bc2(2.f * wq.w);
#pragma unroll
        for (int k = 0; k < 4; k++) {
            const f32x2v evx = bc2(ev[k].x), evy = bc2(ev[k].y);
            const f32x2v evz = bc2(ev[k].z), evw = bc2(ev[k].w);
#pragma unroll
            for (int p = 0; p < 2; p++) {
                const f32x2v a1 = __builtin_elementwise_fma(ep[0][p], evx, one);
                const f32x2v b1 = __builtin_elementwise_fma(ep[1][p], evy, one);
                const f32x2v c1 = __builtin_elementwise_fma(ep[2][p], evz, one);
                const f32x2v d1 = __builtin_elementwise_fma(ep[3][p], evw, one);
                const f32x2v pab = a1 * b1, pcd = c1 * d1;
                const f32x2v nab = __builtin_elementwise_fma(a1, w1p, b1 * w0p);
                const f32x2v ncd = __builtin_elementwise_fma(c1, w3p, d1 * w2p);
                const f32x2v num = __builtin_elementwise_fma(nab, pcd, ncd * pab);
                const f32x2v den = pab * pcd;
                const f32x2v r = {__builtin_amdgcn_rcpf(den[0]), __builtin_amdgcn_rcpf(den[1])};
                acc[k][p] = __builtin_elementwise_fma(num, r, acc[k][p]);
            }
        }
#pragma unroll
        for (int k = 0; k < 4; k++) ev[k] = evn[k];
    }

    // combine u-halves via cbuf[q][v] (q-major, lane-consecutive b32)
    float* cb = scratch;   // [16 q][512 v]
    if (uh == 1) {
#pragma unroll
        for (int p = 0; p < 2; p++)
#pragma unroll
            for (int k = 0; k < 4; k++) {
                cb[(qq * 4 + 2 * p + 0) * 512 + vgrp + k * 128] = acc[k][p][0];
                cb[(qq * 4 + 2 * p + 1) * 512 + vgrp + k * 128] = acc[k][p][1];
            }
    }
    __syncthreads();
    if (uh == 0) {
#pragma unroll
        for (int p = 0; p < 2; p++)
#pragma unroll
            for (int k = 0; k < 4; k++) {
                const float hx = cb[(qq * 4 + 2 * p + 0) * 512 + vgrp + k * 128];
                const float hy = cb[(qq * 4 + 2 * p + 1) * 512 + vgrp + k * 128];
                float2 e;
                e.x = __builtin_amdgcn_exp2f((vsum - (acc[k][p][0] + hx)) * LOG2E);
                e.y = __builtin_amdgcn_exp2f((vsum - (acc[k][p][1] + hy)) * LOG2E);
                *(float2*)&att[vgrp + k * 128][qq * 4 + 2 * p] = e;
                acc[k][p] = (f32x2v){e.x, e.y};
            }
        // denom partials: combine the 4 v-offsets, then butterfly over 64 lanes
        float2 s[2];
#pragma unroll
        for (int p = 0; p < 2; p++) {
            s[p].x = acc[0][p][0] + acc[1][p][0] + acc[2][p][0] + acc[3][p][0];
            s[p].y = acc[0][p][1] + acc[1][p][1] + acc[2][p][1] + acc[3][p][1];
        }
#pragma unroll
        for (int off = 1; off < 64; off <<= 1) {
#pragma unroll
            for (int p = 0; p < 2; p++) {
                s[p].x += __shfl_xor(s[p].x, off, 64);
                s[p].y += __shfl_xor(s[p].y, off, 64);
            }
        }
        if ((tid & 63) == 0) {
            const int w = tid >> 6;   // 0..7 (uh=0): waves (2m,2m+1) share qq=m
#pragma unroll
            for (int p = 0; p < 2; p++) {
                wred[w][2 * p + 0] = s[p].x;
                wred[w][2 * p + 1] = s[p].y;
            }
        }
    }
    __syncthreads();
    if (tid < 16) {
        const int qq2 = tid >> 2, j = tid & 3;   // q = qq2*4 + j
        atomicAdd(&denom[b * QQ + qbase + tid],
                  wred[2 * qq2][j] + wred[2 * qq2 + 1][j]);
    }

    // ---- Phase B: (qh: 8 q, vh: 4 v-quarters of 128) across 8 half-waves ----
    const int hg = tid & 127, sel = tid >> 7;       // sel wave-uniform
    const int qhb = sel & 1, vh = sel >> 1;         // vh 0..3
    const int h0 = hg * 4;
    const float* vp = values + ((size_t)(b * VV + vbase + vh * 128)) * HH + h0;

    float4 oacc[8];
#pragma unroll
    for (int j = 0; j < 8; j++) oacc[j] = make_float4(0.f, 0.f, 0.f, 0.f);

#pragma unroll 2
    for (int vv = 0; vv < 128; vv++) {
        const float4 w = *(const float4*)&vp[(size_t)vv * HH];
        const float4 a0 = *(const float4*)&att[vh * 128 + vv][qhb * 8 + 0];  // broadcast
        const float4 a1 = *(const float4*)&att[vh * 128 + vv][qhb * 8 + 4];
        fma4(oacc[0], a0.x, w); fma4(oacc[1], a0.y, w);
        fma4(oacc[2], a0.z, w); fma4(oacc[3], a0.w, w);
        fma4(oacc[4], a1.x, w); fma4(oacc[5], a1.y, w);
        fma4(oacc[6], a1.z, w); fma4(oacc[7], a1.w, w);
    }

    // epilogue: 2 rounds over qh; vh 1..3 stage to 3 LDS buffers, vh 0 sums+stores
    float (*scr)[512] = (float(*)[512])scratch;   // 24 rows x 512
    for (int rr = 0; rr < 2; rr++) {
        __syncthreads();
        if (qhb == rr && vh > 0) {
#pragma unroll
            for (int j = 0; j < 8; j++)
                *(float4*)&scr[(vh - 1) * 8 + j][h0] = oacc[j];
        }
        __syncthreads();
        if (qhb == rr && vh == 0) {
            float* sp = slab + (size_t)vs * (BB * QQ * HH);
#pragma unroll
            for (int j = 0; j < 8; j++) {
                const float4 p0 = *(const float4*)&scr[0 * 8 + j][h0];
                const float4 p1 = *(const float4*)&scr[1 * 8 + j][h0];
                const float4 p2 = *(const float4*)&scr[2 * 8 + j][h0];
                float4 o;
                o.x = oacc[j].x + p0.x + p1.x + p2.x;
                o.y = oacc[j].y + p0.y + p1.y + p2.y;
                o.z = oacc[j].z + p0.z + p1.z + p2.z;
                o.w = oacc[j].w + p0.w + p1.w + p2.w;
                *(float4*)&sp[((size_t)(b * QQ + qbase + rr * 8 + j)) * HH + h0] = o;
            }
        }
    }
}

// ---------------------------------------------------------------------------
// out = (sum of 4 slabs) * rcp(denom[row]). 131072 float4s, grid 512.
// ---------------------------------------------------------------------------
__global__ __launch_bounds__(256) void reduce_kernel(const float* __restrict__ slab,
                                                     const float* __restrict__ denom,
                                                     float* __restrict__ out) {
    const int i = blockIdx.x * 256 + threadIdx.x;    // float4 index
    const float r = __builtin_amdgcn_rcpf(denom[i >> 7]);
    const float4* s4 = (const float4*)slab;
    float4 s = s4[i];
#pragma unroll
    for (int k = 1; k < 4; k++) {
        const float4 p = s4[(size_t)k * (BB * QQ * HH / 4) + i];
        s.x += p.x; s.y += p.y; s.z += p.z; s.w += p.w;
    }
    s.x *= r; s.y *= r; s.z *= r; s.w *= r;
    ((float4*)out)[i] = s;
}

// ---------------------------------------------------------------------------
extern "C" void kernel_launch(void* const* d_in, const int* in_sizes, int n_in,
                              void* d_out, int out_size, void* d_ws, size_t ws_size,
                              hipStream_t stream) {
    const float* queries = (const float*)d_in[0];  // [B,Q,H]
    const float* values  = (const float*)d_in[1];  // [B,V,H]
    const float* w1      = (const float*)d_in[2];  // [H,U]
    const float* w2      = (const float*)d_in[3];  // [H,U]
    const float* vvec    = (const float*)d_in[4];  // [U]
    float* out = (float*)d_out;

    // ws (floats): pqI[131072] | pvI[1048576] | denom[1024] | slab[4*524288]
    float* ws    = (float*)d_ws;
    float* pqI   = ws;
    float* pvI   = pqI + BB * UU * QQ;
    float* denom = pvI + (size_t)BB * UU * VV;
    float* slab  = denom + BB * QQ;

    proj_kernel<<<256 + 32, 256, 0, stream>>>(queries, values, w1, w2, pqI, pvI, denom);
    fused_kernel<<<BB * (QQ / 16) * (VV / 512), 1024, 0, stream>>>(pqI, pvI, vvec, values, slab, denom);
    reduce_kernel<<<(BB * QQ * HH) / 4 / 256, 256, 0, stream>>>(slab, denom, out);
}